// Round 2
// baseline (932.862 us; speedup 1.0000x reference)
//
#include <hip/hip_runtime.h>
#include <hip/hip_bf16.h>

#define B_SZ   4096
#define S_LEN  200
#define EMB    300
#define TAGS   2

// ---------------------------------------------------------------------------
// Kernel 1: pooled[b][d] = mean_t emb[x[b][t]][d]
// one block per batch row; 256 threads cover 300 dims (tid and tid+256)
// ---------------------------------------------------------------------------
__global__ __launch_bounds__(256)
void gather_mean_kernel(const int* __restrict__ x,
                        const float* __restrict__ emb,
                        float* __restrict__ pooled) {
    const int b   = blockIdx.x;
    const int tid = threadIdx.x;

    __shared__ int ids[S_LEN];
    if (tid < S_LEN) ids[tid] = x[b * S_LEN + tid];
    __syncthreads();

    const int  d0   = tid;            // 0..255
    const int  d1   = tid + 256;      // 256..299 valid for tid < 44
    const bool has2 = (d1 < EMB);

    float acc0 = 0.f, acc1 = 0.f;
#pragma unroll 8
    for (int t = 0; t < S_LEN; ++t) {
        const long base = (long)ids[t] * EMB;
        acc0 += emb[base + d0];
        if (has2) acc1 += emb[base + d1];
    }
    const float inv = 1.0f / (float)S_LEN;
    pooled[(long)b * EMB + d0] = acc0 * inv;
    if (has2) pooled[(long)b * EMB + d1] = acc1 * inv;
}

// ---------------------------------------------------------------------------
// Kernels 2/3: C = relu(A @ W^T)   A:[M][K] row-major, W:[N][K] row-major
// 64x64 tile, BK=16, 256 threads, 4x4 register micro-tile
// ---------------------------------------------------------------------------
#define BM 64
#define BN 64
#define BK 16

template <bool RELU>
__global__ __launch_bounds__(256)
void gemm_tn_kernel(const float* __restrict__ A,
                    const float* __restrict__ W,
                    float* __restrict__ C,
                    int M, int N, int K) {
    __shared__ float As[BM][BK + 1];
    __shared__ float Ws[BN][BK + 1];

    const int tid = threadIdx.x;
    const int tx  = tid % 16;      // col group
    const int ty  = tid / 16;      // row group
    const int m0  = blockIdx.x * BM;
    const int n0  = blockIdx.y * BN;

    float acc[4][4] = {};

    for (int k0 = 0; k0 < K; k0 += BK) {
        // --- stage A tile: 64 rows x 16 cols, float4 per thread ---
        {
            const int r  = tid / 4;            // 0..63
            const int c  = (tid % 4) * 4;      // 0,4,8,12
            const int gk = k0 + c;
            float4 v = make_float4(0.f, 0.f, 0.f, 0.f);
            const long off = (long)(m0 + r) * K + gk;
            if (gk + 3 < K) {
                v = *(const float4*)&A[off];
            } else {
                float t0 = (gk + 0 < K) ? A[off + 0] : 0.f;
                float t1 = (gk + 1 < K) ? A[off + 1] : 0.f;
                float t2 = (gk + 2 < K) ? A[off + 2] : 0.f;
                float t3 = (gk + 3 < K) ? A[off + 3] : 0.f;
                v = make_float4(t0, t1, t2, t3);
            }
            As[r][c + 0] = v.x; As[r][c + 1] = v.y;
            As[r][c + 2] = v.z; As[r][c + 3] = v.w;
        }
        // --- stage W tile: 64 rows (N) x 16 cols (K) ---
        {
            const int r  = tid / 4;
            const int c  = (tid % 4) * 4;
            const int gn = n0 + r;
            const int gk = k0 + c;
            float4 v = make_float4(0.f, 0.f, 0.f, 0.f);
            if (gn < N) {
                const long off = (long)gn * K + gk;
                if (gk + 3 < K) {
                    v = *(const float4*)&W[off];
                } else {
                    float t0 = (gk + 0 < K) ? W[off + 0] : 0.f;
                    float t1 = (gk + 1 < K) ? W[off + 1] : 0.f;
                    float t2 = (gk + 2 < K) ? W[off + 2] : 0.f;
                    float t3 = (gk + 3 < K) ? W[off + 3] : 0.f;
                    v = make_float4(t0, t1, t2, t3);
                }
            }
            Ws[r][c + 0] = v.x; Ws[r][c + 1] = v.y;
            Ws[r][c + 2] = v.z; Ws[r][c + 3] = v.w;
        }
        __syncthreads();

#pragma unroll
        for (int kk = 0; kk < BK; ++kk) {
            float a[4], bb[4];
#pragma unroll
            for (int i = 0; i < 4; ++i) a[i]  = As[ty * 4 + i][kk];
#pragma unroll
            for (int j = 0; j < 4; ++j) bb[j] = Ws[tx * 4 + j][kk];
#pragma unroll
            for (int i = 0; i < 4; ++i)
#pragma unroll
                for (int j = 0; j < 4; ++j)
                    acc[i][j] = fmaf(a[i], bb[j], acc[i][j]);
        }
        __syncthreads();
    }

    // --- epilogue ---
#pragma unroll
    for (int i = 0; i < 4; ++i) {
        const int gm = m0 + ty * 4 + i;   // M divisible by 64: always valid
#pragma unroll
        for (int j = 0; j < 4; ++j) {
            const int gn = n0 + tx * 4 + j;
            if (gn < N) {
                float v = acc[i][j];
                if (RELU) v = fmaxf(v, 0.f);
                C[(long)gm * N + gn] = v;
            }
        }
    }
}

// ---------------------------------------------------------------------------
// Kernel 4: out[b][t] = sum_k H[b][k] * w3[t][k]   (t = 0,1)
// one wave per row, shuffle reduce
// ---------------------------------------------------------------------------
__global__ __launch_bounds__(256)
void final_kernel(const float* __restrict__ H,
                  const float* __restrict__ w3,
                  float* __restrict__ out) {
    const int wave = threadIdx.x >> 6;       // 0..3
    const int lane = threadIdx.x & 63;
    const int row  = blockIdx.x * 4 + wave;
    if (row >= B_SZ) return;

    float a0 = 0.f, a1 = 0.f;
    for (int k = lane; k < EMB; k += 64) {
        const float h = H[(long)row * EMB + k];
        a0 += h * w3[k];
        a1 += h * w3[EMB + k];
    }
#pragma unroll
    for (int off = 32; off > 0; off >>= 1) {
        a0 += __shfl_down(a0, off);
        a1 += __shfl_down(a1, off);
    }
    if (lane == 0) {
        out[row * TAGS + 0] = a0;
        out[row * TAGS + 1] = a1;
    }
}

// ---------------------------------------------------------------------------
extern "C" void kernel_launch(void* const* d_in, const int* in_sizes, int n_in,
                              void* d_out, int out_size, void* d_ws, size_t ws_size,
                              hipStream_t stream) {
    const int*   x   = (const int*)d_in[0];
    const float* emb = (const float*)d_in[1];
    const float* w1  = (const float*)d_in[2];
    const float* w2  = (const float*)d_in[3];
    const float* w3  = (const float*)d_in[4];
    float*       out = (float*)d_out;

    float* pooled = (float*)d_ws;                       // [4096][300]
    float* h1     = pooled + (long)B_SZ * EMB;          // [4096][300]
    // h2 reuses the pooled buffer (pooled is dead after layer 1)

    gather_mean_kernel<<<B_SZ, 256, 0, stream>>>(x, emb, pooled);

    dim3 gemm_grid(B_SZ / BM, (EMB + BN - 1) / BN);     // 64 x 5
    gemm_tn_kernel<true><<<gemm_grid, 256, 0, stream>>>(pooled, w1, h1, B_SZ, EMB, EMB);
    gemm_tn_kernel<true><<<gemm_grid, 256, 0, stream>>>(h1, w2, pooled, B_SZ, EMB, EMB);

    final_kernel<<<(B_SZ + 3) / 4, 256, 0, stream>>>(pooled, w3, out);
}

// Round 8
// 829.652 us; speedup vs baseline: 1.1244x; 1.1244x over previous
//
#include <hip/hip_runtime.h>
#include <hip/hip_bf16.h>

#define B_SZ   4096
#define S_LEN  200
#define EMB    300
#define TAGS   2

// ---------------------------------------------------------------------------
// Kernel 1: pooled[b][d] = mean_t emb[x[b][t]][d]
// One block (4 waves) per batch row. Wave w owns tokens t = w, w+4, ... (50).
// Lane l loads float4 at dim 4l (dims 0..255); lanes 0..10 also load the
// float4 at dim 256+4l (dims 256..299). Cross-wave reduce via LDS.
// ---------------------------------------------------------------------------
__global__ __launch_bounds__(256)
void gather_mean_kernel(const int* __restrict__ x,
                        const float* __restrict__ emb,
                        float* __restrict__ pooled) {
    const int b    = blockIdx.x;
    const int tid  = threadIdx.x;
    const int wave = tid >> 6;
    const int lane = tid & 63;

    __shared__ int   ids[S_LEN];
    __shared__ float part[4][EMB + 4];   // row stride 304 floats (16B aligned)

    if (tid < S_LEN) ids[tid] = x[b * S_LEN + tid];
    __syncthreads();

    float4 acc0 = make_float4(0.f, 0.f, 0.f, 0.f);
    float4 acc1 = make_float4(0.f, 0.f, 0.f, 0.f);
    const bool has2 = (lane < (EMB - 256 + 3) / 4);   // lanes 0..10

#pragma unroll 2
    for (int i = 0; i < S_LEN / 4; ++i) {
        const int  t    = wave + 4 * i;
        const long base = (long)ids[t] * EMB;
        const float4 v0 = *(const float4*)&emb[base + 4 * lane];
        acc0.x += v0.x; acc0.y += v0.y; acc0.z += v0.z; acc0.w += v0.w;
        if (has2) {
            const float4 v1 = *(const float4*)&emb[base + 256 + 4 * lane];
            acc1.x += v1.x; acc1.y += v1.y; acc1.z += v1.z; acc1.w += v1.w;
        }
    }

    *(float4*)&part[wave][4 * lane] = acc0;
    if (has2) *(float4*)&part[wave][256 + 4 * lane] = acc1;
    __syncthreads();

    const float inv = 1.0f / (float)S_LEN;
    {
        const float s = part[0][tid] + part[1][tid] + part[2][tid] + part[3][tid];
        pooled[(long)b * EMB + tid] = s * inv;
    }
    if (tid < EMB - 256) {
        const int d = 256 + tid;
        const float s = part[0][d] + part[1][d] + part[2][d] + part[3][d];
        pooled[(long)b * EMB + d] = s * inv;
    }
}

// ---------------------------------------------------------------------------
// Kernels 2/3: C = relu(A @ W^T)   A:[M][K] row-major, W:[N][K] row-major
// 64x64 tile, BK=16, 512 threads (8 waves), 4x2 register micro-tile.
// LDS is k-major ([BK][stride 68]) so fragment reads are ds_read_b128/b64.
// Threads 0..255 stage the A tile; threads 256..511 stage the W tile.
// ---------------------------------------------------------------------------
#define BM   64
#define BN   64
#define BK   16
#define LDST 68   // 68 % 32 == 4: staging writes 2-way (free), reads clean

template <bool RELU>
__global__ __launch_bounds__(512)
void gemm_tn_kernel(const float* __restrict__ A,
                    const float* __restrict__ W,
                    float* __restrict__ C,
                    int M, int N, int K) {
    __shared__ float As[BK][LDST];
    __shared__ float Ws[BK][LDST];

    const int tid = threadIdx.x;
    const int tx  = tid & 31;        // n-group: 2 cols each
    const int ty  = tid >> 5;        // m-group: 4 rows each (0..15)
    const int m0  = blockIdx.x * BM;
    const int n0  = blockIdx.y * BN;

    const bool stageA = (tid < 256);
    const int  s  = stageA ? tid : tid - 256;
    const int  sr = s >> 2;          // 0..63 tile row
    const int  sc = (s & 3) * 4;     // 0,4,8,12 k-offset

    float acc[4][2] = {};

    for (int k0 = 0; k0 < K; k0 += BK) {
        // ---- stage (transposed into k-major LDS) ----
        {
            const int    gk   = k0 + sc;
            const float* src  = stageA ? A : W;
            const int    grow = stageA ? (m0 + sr) : (n0 + sr);
            float4 v = make_float4(0.f, 0.f, 0.f, 0.f);
            const bool rowok = stageA ? true : (grow < N);
            if (rowok) {
                const long off = (long)grow * K + gk;
                if (gk + 3 < K) {
                    v = *(const float4*)&src[off];
                } else {
                    if (gk + 0 < K) v.x = src[off + 0];
                    if (gk + 1 < K) v.y = src[off + 1];
                    if (gk + 2 < K) v.z = src[off + 2];
                    if (gk + 3 < K) v.w = src[off + 3];
                }
            }
            float (*dst)[LDST] = stageA ? As : Ws;
            dst[sc + 0][sr] = v.x;
            dst[sc + 1][sr] = v.y;
            dst[sc + 2][sr] = v.z;
            dst[sc + 3][sr] = v.w;
        }
        __syncthreads();

#pragma unroll
        for (int kk = 0; kk < BK; ++kk) {
            const float4 a  = *(const float4*)&As[kk][ty * 4];
            const float2 bb = *(const float2*)&Ws[kk][tx * 2];
            acc[0][0] = fmaf(a.x, bb.x, acc[0][0]);
            acc[0][1] = fmaf(a.x, bb.y, acc[0][1]);
            acc[1][0] = fmaf(a.y, bb.x, acc[1][0]);
            acc[1][1] = fmaf(a.y, bb.y, acc[1][1]);
            acc[2][0] = fmaf(a.z, bb.x, acc[2][0]);
            acc[2][1] = fmaf(a.z, bb.y, acc[2][1]);
            acc[3][0] = fmaf(a.w, bb.x, acc[3][0]);
            acc[3][1] = fmaf(a.w, bb.y, acc[3][1]);
        }
        __syncthreads();
    }

#pragma unroll
    for (int i = 0; i < 4; ++i) {
        const int gm = m0 + ty * 4 + i;            // M % 64 == 0: valid
#pragma unroll
        for (int j = 0; j < 2; ++j) {
            const int gn = n0 + tx * 2 + j;
            if (gn < N) {
                float v = acc[i][j];
                if (RELU) v = fmaxf(v, 0.f);
                C[(long)gm * N + gn] = v;
            }
        }
    }
}

// ---------------------------------------------------------------------------
// Kernel 4: out[b][t] = sum_k H[b][k] * w3[t][k]   (t = 0,1)
// one wave per row, shuffle reduce
// ---------------------------------------------------------------------------
__global__ __launch_bounds__(256)
void final_kernel(const float* __restrict__ H,
                  const float* __restrict__ w3,
                  float* __restrict__ out) {
    const int wave = threadIdx.x >> 6;       // 0..3
    const int lane = threadIdx.x & 63;
    const int row  = blockIdx.x * 4 + wave;
    if (row >= B_SZ) return;

    float a0 = 0.f, a1 = 0.f;
    for (int k = lane; k < EMB; k += 64) {
        const float h = H[(long)row * EMB + k];
        a0 += h * w3[k];
        a1 += h * w3[EMB + k];
    }
#pragma unroll
    for (int off = 32; off > 0; off >>= 1) {
        a0 += __shfl_down(a0, off);
        a1 += __shfl_down(a1, off);
    }
    if (lane == 0) {
        out[row * TAGS + 0] = a0;
        out[row * TAGS + 1] = a1;
    }
}

// ---------------------------------------------------------------------------
extern "C" void kernel_launch(void* const* d_in, const int* in_sizes, int n_in,
                              void* d_out, int out_size, void* d_ws, size_t ws_size,
                              hipStream_t stream) {
    const int*   x   = (const int*)d_in[0];
    const float* emb = (const float*)d_in[1];
    const float* w1  = (const float*)d_in[2];
    const float* w2  = (const float*)d_in[3];
    const float* w3  = (const float*)d_in[4];
    float*       out = (float*)d_out;

    float* pooled = (float*)d_ws;                       // [4096][300]
    float* h1     = pooled + (long)B_SZ * EMB;          // [4096][300]
    // h2 reuses the pooled buffer (pooled is dead after layer 1)

    gather_mean_kernel<<<B_SZ, 256, 0, stream>>>(x, emb, pooled);

    dim3 gemm_grid(B_SZ / BM, (EMB + BN - 1) / BN);     // 64 x 5
    gemm_tn_kernel<true><<<gemm_grid, 512, 0, stream>>>(pooled, w1, h1, B_SZ, EMB, EMB);
    gemm_tn_kernel<true><<<gemm_grid, 512, 0, stream>>>(h1, w2, pooled, B_SZ, EMB, EMB);

    final_kernel<<<(B_SZ + 3) / 4, 256, 0, stream>>>(pooled, w3, out);
}